// Round 1
// baseline (3965.444 us; speedup 1.0000x reference)
//
#include <hip/hip_runtime.h>

#define NP 200000
#define NA 100000
#define NE 400000
#define HH 2
#define DD 32
#define FF 64
#define INDIM 128
#define KQV 192

// order-preserving float<->uint encoding for atomicMax on floats
__device__ __forceinline__ unsigned enc_f(float f) {
    unsigned u = __float_as_uint(f);
    return (u & 0x80000000u) ? ~u : (u | 0x80000000u);
}
__device__ __forceinline__ float dec_f(unsigned u) {
    return (u & 0x80000000u) ? __uint_as_float(u & 0x7FFFFFFFu)
                             : __uint_as_float(~u);
}

// Y = act(X @ W + b), X:[N,FIN], W:[FIN,FOUT], 256 threads, 4 rows/iter,
// lane (0..63) = output column (FOUT/64 cols per thread). W staged in LDS.
template <int FIN, int FOUT, bool RELU>
__global__ void lin_kernel(const float* __restrict__ X, const float* __restrict__ W,
                           const float* __restrict__ b, float* __restrict__ Y, int N) {
    __shared__ float Ws[FIN * FOUT];
    __shared__ float Xs[4][FIN];
    for (int i = threadIdx.x; i < FIN * FOUT; i += blockDim.x) Ws[i] = W[i];
    const int lane = threadIdx.x & 63;
    const int rloc = threadIdx.x >> 6;  // 0..3 (wave id)
    float breg[FOUT / 64];
#pragma unroll
    for (int j = 0; j < FOUT / 64; ++j) breg[j] = b[lane + 64 * j];
    __syncthreads();
    for (int base = blockIdx.x * 4; base < N; base += gridDim.x * 4) {
        __syncthreads();
        for (int i = threadIdx.x; i < 4 * FIN; i += blockDim.x) {
            int r = base + i / FIN;
            Xs[i / FIN][i % FIN] = (r < N) ? X[(size_t)r * FIN + (i % FIN)] : 0.f;
        }
        __syncthreads();
        int row = base + rloc;
        if (row < N) {
            float acc[FOUT / 64];
#pragma unroll
            for (int j = 0; j < FOUT / 64; ++j) acc[j] = breg[j];
            for (int i = 0; i < FIN; ++i) {
                float xv = Xs[rloc][i];
#pragma unroll
                for (int j = 0; j < FOUT / 64; ++j)
                    acc[j] = fmaf(xv, Ws[i * FOUT + lane + 64 * j], acc[j]);
            }
#pragma unroll
            for (int j = 0; j < FOUT / 64; ++j) {
                float v = acc[j];
                if (RELU) v = fmaxf(v, 0.f);
                Y[(size_t)row * FOUT + lane + 64 * j] = v;
            }
        }
    }
}

// Pass 1: logits per (edge, head) + atomic segment max.
// kqv layout per node: [k(64) | q(64) | v(64)], k/q/v each [H=2][D=32].
__global__ void edge_logits(const float* __restrict__ kqv_src,
                            const float* __restrict__ kqv_dstq,
                            const int* __restrict__ src, const int* __restrict__ dst,
                            const float* __restrict__ Wk, const float* __restrict__ p,
                            float* __restrict__ logits, unsigned* __restrict__ Menc,
                            int nE, int egoff) {
    __shared__ float Wks[HH * DD * DD];
    for (int i = threadIdx.x; i < HH * DD * DD; i += blockDim.x) Wks[i] = Wk[i];
    __syncthreads();
    const float scale = 0.1767766952966369f;  // 1/sqrt(32)
    float ph0 = p[0] * scale, ph1 = p[1] * scale;
    int stride = gridDim.x * blockDim.x;
    for (int idx = blockIdx.x * blockDim.x + threadIdx.x; idx < nE * HH; idx += stride) {
        int e = idx >> 1, h = idx & 1;
        int s = src[e], dn = dst[e];
        const float* kp = kqv_src + (size_t)s * KQV + h * DD;
        const float* qp = kqv_dstq + (size_t)dn * KQV + 64 + h * DD;
        float kreg[DD], qreg[DD];
#pragma unroll
        for (int i = 0; i < DD; ++i) kreg[i] = kp[i];
#pragma unroll
        for (int i = 0; i < DD; ++i) qreg[i] = qp[i];
        const float* Wh = Wks + h * DD * DD;
        float logit = 0.f;
        for (int f = 0; f < DD; ++f) {
            float kf = 0.f;
#pragma unroll
            for (int d2 = 0; d2 < DD; ++d2) kf = fmaf(kreg[d2], Wh[d2 * DD + f], kf);
            logit = fmaf(qreg[f], kf, logit);
        }
        logit *= (h ? ph1 : ph0);
        logits[(size_t)(egoff + e) * HH + h] = logit;
        atomicMax(Menc + (size_t)dn * HH + h, enc_f(logit));
    }
}

// Pass 2: e = exp(l - M); accumulate S and unnormalized agg (v-transform).
__global__ void edge_agg(const float* __restrict__ kqv_src,
                         const int* __restrict__ src, const int* __restrict__ dst,
                         const float* __restrict__ Wv,
                         const float* __restrict__ logits,
                         const unsigned* __restrict__ Menc,
                         float* __restrict__ S, float* __restrict__ aggU,
                         int nE, int egoff) {
    __shared__ float Wvs[HH * DD * DD];
    for (int i = threadIdx.x; i < HH * DD * DD; i += blockDim.x) Wvs[i] = Wv[i];
    __syncthreads();
    int stride = gridDim.x * blockDim.x;
    for (int idx = blockIdx.x * blockDim.x + threadIdx.x; idx < nE * HH; idx += stride) {
        int e = idx >> 1, h = idx & 1;
        int s = src[e], dn = dst[e];
        float l = logits[(size_t)(egoff + e) * HH + h];
        float m = dec_f(Menc[(size_t)dn * HH + h]);
        float ev = expf(l - m);
        atomicAdd(S + (size_t)dn * HH + h, ev);
        const float* vp = kqv_src + (size_t)s * KQV + 128 + h * DD;
        float vreg[DD];
#pragma unroll
        for (int i = 0; i < DD; ++i) vreg[i] = vp[i];
        const float* Wh = Wvs + h * DD * DD;
        float* aggp = aggU + (size_t)dn * FF + h * DD;
        for (int f = 0; f < DD; ++f) {
            float vf = 0.f;
#pragma unroll
            for (int d2 = 0; d2 < DD; ++d2) vf = fmaf(vreg[d2], Wh[d2 * DD + f], vf);
            atomicAdd(aggp + f, ev * vf);
        }
    }
}

// Epilogue: normalize, gelu, @a_W_paper + b, skip-mix with xp, @out_W + out_b.
__global__ void finalize_k(const float* __restrict__ aggU, const float* __restrict__ S,
                           const float* __restrict__ xp,
                           const float* __restrict__ aW, const float* __restrict__ ab,
                           const float* __restrict__ skip,
                           const float* __restrict__ outW, const float* __restrict__ outb,
                           float* __restrict__ out) {
    __shared__ float As[FF * FF];
    __shared__ float oWs[FF];
    __shared__ float Gs[4][FF];
    for (int i = threadIdx.x; i < FF * FF; i += blockDim.x) As[i] = aW[i];
    if (threadIdx.x < FF) oWs[threadIdx.x] = outW[threadIdx.x];
    __syncthreads();
    float sp = 1.f / (1.f + expf(-skip[0]));
    float ob = outb[0];
    int lane = threadIdx.x & 63;
    int rloc = threadIdx.x >> 6;
    float abv = ab[lane];
    for (int base = blockIdx.x * 4; base < NP; base += gridDim.x * 4) {
        int row = base + rloc;
        __syncthreads();
        if (row < NP) {
            int h = lane >> 5;
            float sv = fmaxf(S[(size_t)row * HH + h], 1e-16f);
            float a = aggU[(size_t)row * FF + lane] / sv;
            Gs[rloc][lane] = 0.5f * a * (1.f + erff(a * 0.7071067811865476f));
        }
        __syncthreads();
        if (row < NP) {
            float acc = abv;
#pragma unroll 8
            for (int c = 0; c < FF; ++c) acc = fmaf(Gs[rloc][c], As[c * FF + lane], acc);
            float hp = sp * acc + (1.f - sp) * xp[(size_t)row * FF + lane];
            float t = hp * oWs[lane];
#pragma unroll
            for (int off = 32; off > 0; off >>= 1) t += __shfl_down(t, off, 64);
            if (lane == 0) out[row] = t + ob;
        }
    }
}

extern "C" void kernel_launch(void* const* d_in, const int* in_sizes, int n_in,
                              void* d_out, int out_size, void* d_ws, size_t ws_size,
                              hipStream_t stream) {
    const float* x_paper  = (const float*)d_in[0];
    const float* x_author = (const float*)d_in[1];
    const int*   w_src    = (const int*)d_in[2];
    const int*   w_dst    = (const int*)d_in[3];
    const int*   c_src    = (const int*)d_in[4];
    const int*   c_dst    = (const int*)d_in[5];
    // d_in[6], d_in[7]: rev edges — dead (only feed deleted author outputs)
    const float* linWp = (const float*)d_in[8];
    const float* linbp = (const float*)d_in[9];
    const float* linWa = (const float*)d_in[10];
    const float* linba = (const float*)d_in[11];
    const float* kqvWp = (const float*)d_in[12];
    const float* kqvbp = (const float*)d_in[13];
    const float* kqvWa = (const float*)d_in[14];
    const float* kqvba = (const float*)d_in[15];
    const float* aWp   = (const float*)d_in[16];
    const float* abp   = (const float*)d_in[17];
    // d_in[18], d_in[19]: a_W_author / a_b_author — dead
    const float* skipp = (const float*)d_in[20];
    // d_in[21]: skip_author — dead
    const float* Wk_w  = (const float*)d_in[22];
    const float* Wv_w  = (const float*)d_in[23];
    const float* p_w   = (const float*)d_in[24];
    const float* Wk_c  = (const float*)d_in[25];
    const float* Wv_c  = (const float*)d_in[26];
    const float* p_c   = (const float*)d_in[27];
    // d_in[28..30]: rev relation weights — dead
    const float* outW  = (const float*)d_in[31];
    const float* outb  = (const float*)d_in[32];
    float* out = (float*)d_out;

    // workspace layout (floats)
    float* ws     = (float*)d_ws;
    float* xp     = ws;                              // NP*64
    float* xa     = xp + (size_t)NP * FF;            // NA*64
    float* kqvp   = xa + (size_t)NA * FF;            // NP*192
    float* kqva   = kqvp + (size_t)NP * KQV;         // NA*192
    float* logits = kqva + (size_t)NA * KQV;         // 2*NE*2
    unsigned* Menc = (unsigned*)(logits + (size_t)2 * NE * HH);  // NP*2
    float* S      = (float*)(Menc + (size_t)NP * HH);            // NP*2
    float* aggU   = S + (size_t)NP * HH;                         // NP*64

    // zero M (0 == minimal encoded float), S, aggU in one contiguous memset
    hipMemsetAsync(Menc, 0, ((size_t)NP * HH * 2 + (size_t)NP * FF) * sizeof(float), stream);

    dim3 blk(256);

    lin_kernel<INDIM, FF, true><<<2048, blk, 0, stream>>>(x_paper, linWp, linbp, xp, NP);
    lin_kernel<INDIM, FF, true><<<2048, blk, 0, stream>>>(x_author, linWa, linba, xa, NA);
    lin_kernel<FF, KQV, false><<<2048, blk, 0, stream>>>(xp, kqvWp, kqvbp, kqvp, NP);
    lin_kernel<FF, KQV, false><<<2048, blk, 0, stream>>>(xa, kqvWa, kqvba, kqva, NA);

    edge_logits<<<2048, blk, 0, stream>>>(kqva, kqvp, w_src, w_dst, Wk_w, p_w, logits, Menc, NE, 0);
    edge_logits<<<2048, blk, 0, stream>>>(kqvp, kqvp, c_src, c_dst, Wk_c, p_c, logits, Menc, NE, NE);

    edge_agg<<<2048, blk, 0, stream>>>(kqva, w_src, w_dst, Wv_w, logits, Menc, S, aggU, NE, 0);
    edge_agg<<<2048, blk, 0, stream>>>(kqvp, c_src, c_dst, Wv_c, logits, Menc, S, aggU, NE, NE);

    finalize_k<<<2048, blk, 0, stream>>>(aggU, S, xp, aWp, abp, skipp, outW, outb, out);
}

// Round 3
// 1997.240 us; speedup vs baseline: 1.9855x; 1.9855x over previous
//
#include <hip/hip_runtime.h>

#define NP 200000
#define NA 100000
#define NE 400000
#define HH 2
#define DD 32
#define FF 64
#define INDIM 128
#define KQV 192

// ---------------- dense linears (unchanged, known-good) ----------------
// Y = act(X @ W + b), X:[N,FIN], W:[FIN,FOUT], 256 threads, 4 rows/iter,
// lane = output column (FOUT/64 cols per thread). W staged in LDS.
template <int FIN, int FOUT, bool RELU>
__global__ void lin_kernel(const float* __restrict__ X, const float* __restrict__ W,
                           const float* __restrict__ b, float* __restrict__ Y, int N) {
    __shared__ float Ws[FIN * FOUT];
    __shared__ float Xs[4][FIN];
    for (int i = threadIdx.x; i < FIN * FOUT; i += blockDim.x) Ws[i] = W[i];
    const int lane = threadIdx.x & 63;
    const int rloc = threadIdx.x >> 6;
    float breg[FOUT / 64];
#pragma unroll
    for (int j = 0; j < FOUT / 64; ++j) breg[j] = b[lane + 64 * j];
    __syncthreads();
    for (int base = blockIdx.x * 4; base < N; base += gridDim.x * 4) {
        __syncthreads();
        for (int i = threadIdx.x; i < 4 * FIN; i += blockDim.x) {
            int r = base + i / FIN;
            Xs[i / FIN][i % FIN] = (r < N) ? X[(size_t)r * FIN + (i % FIN)] : 0.f;
        }
        __syncthreads();
        int row = base + rloc;
        if (row < N) {
            float acc[FOUT / 64];
#pragma unroll
            for (int j = 0; j < FOUT / 64; ++j) acc[j] = breg[j];
            for (int i = 0; i < FIN; ++i) {
                float xv = Xs[rloc][i];
#pragma unroll
                for (int j = 0; j < FOUT / 64; ++j)
                    acc[j] = fmaf(xv, Ws[i * FOUT + lane + 64 * j], acc[j]);
            }
#pragma unroll
            for (int j = 0; j < FOUT / 64; ++j) {
                float v = acc[j];
                if (RELU) v = fmaxf(v, 0.f);
                Y[(size_t)row * FOUT + lane + 64 * j] = v;
            }
        }
    }
}

// Author kqv: compute only k (cols 0..63) and v (cols 128..191) of W[64][192].
// Output layout [NA][128]: k | v.
__global__ void lin_kv_kernel(const float* __restrict__ X, const float* __restrict__ W,
                              const float* __restrict__ b, float* __restrict__ Y, int N) {
    __shared__ float Ws[64 * 128];
    __shared__ float Xs[4][64];
    for (int i = threadIdx.x; i < 64 * 128; i += blockDim.x) {
        int r = i >> 7, c = i & 127;
        Ws[i] = W[r * 192 + c + ((c >> 6) << 6)];  // c<64 -> c (k), else c+64 (v)
    }
    const int lane = threadIdx.x & 63;
    const int rloc = threadIdx.x >> 6;
    float breg[2];
    breg[0] = b[lane];
    breg[1] = b[lane + 128];
    __syncthreads();
    for (int base = blockIdx.x * 4; base < N; base += gridDim.x * 4) {
        __syncthreads();
        for (int i = threadIdx.x; i < 4 * 64; i += blockDim.x) {
            int r = base + (i >> 6);
            Xs[i >> 6][i & 63] = (r < N) ? X[(size_t)r * 64 + (i & 63)] : 0.f;
        }
        __syncthreads();
        int row = base + rloc;
        if (row < N) {
            float acc[2] = {breg[0], breg[1]};
            for (int i = 0; i < 64; ++i) {
                float xv = Xs[rloc][i];
                acc[0] = fmaf(xv, Ws[i * 128 + lane], acc[0]);
                acc[1] = fmaf(xv, Ws[i * 128 + 64 + lane], acc[1]);
            }
            Y[(size_t)row * 128 + lane] = acc[0];
            Y[(size_t)row * 128 + 64 + lane] = acc[1];
        }
    }
}

// ---------------- CSR build ----------------
__global__ void deg_count(const int* __restrict__ d1, const int* __restrict__ d2,
                          int* __restrict__ deg) {
    int i = blockIdx.x * blockDim.x + threadIdx.x;
    if (i < 2 * NE) {
        int d = (i < NE) ? d1[i] : d2[i - NE];
        atomicAdd(deg + d, 1);
    }
}

__device__ __forceinline__ int block_excl_scan_256(int v) {
    __shared__ int wsum[4];
    int lane = threadIdx.x & 63, wv = threadIdx.x >> 6;
    int incl = v;
#pragma unroll
    for (int off = 1; off < 64; off <<= 1) {
        int t = __shfl_up(incl, off, 64);
        if (lane >= off) incl += t;
    }
    if (lane == 63) wsum[wv] = incl;
    __syncthreads();
    int wo = 0;
#pragma unroll
    for (int k = 0; k < 4; ++k) wo += (k < wv) ? wsum[k] : 0;
    __syncthreads();
    return wo + incl - v;
}

__global__ void scan_bsum(const int* __restrict__ deg, int* __restrict__ bsum, int n) {
    __shared__ int wsum[4];
    int i = blockIdx.x * 256 + threadIdx.x;
    int v = (i < n) ? deg[i] : 0;
#pragma unroll
    for (int off = 32; off > 0; off >>= 1) v += __shfl_xor(v, off, 64);
    int lane = threadIdx.x & 63, wv = threadIdx.x >> 6;
    if (lane == 0) wsum[wv] = v;
    __syncthreads();
    if (threadIdx.x == 0) bsum[blockIdx.x] = wsum[0] + wsum[1] + wsum[2] + wsum[3];
}

__global__ void scan_mid(int* __restrict__ bsum, int nb) {
    __shared__ int carry;
    if (threadIdx.x == 0) carry = 0;
    __syncthreads();
    for (int base = 0; base < nb; base += 256) {
        int i = base + threadIdx.x;
        int v = (i < nb) ? bsum[i] : 0;
        int ex = block_excl_scan_256(v);
        int c = carry;
        __syncthreads();
        if (i < nb) bsum[i] = ex + c;
        if (threadIdx.x == 255) carry = c + ex + v;
        __syncthreads();
    }
}

__global__ void scan_final(const int* __restrict__ deg, const int* __restrict__ bsum,
                           int* __restrict__ row_ptr, int* __restrict__ cursor, int n) {
    int i = blockIdx.x * 256 + threadIdx.x;
    int v = (i < n) ? deg[i] : 0;
    int ex = block_excl_scan_256(v) + bsum[blockIdx.x];
    if (i < n) { row_ptr[i] = ex; cursor[i] = ex; }
}

__global__ void scatter_edges(const int* __restrict__ src, const int* __restrict__ dst,
                              int* __restrict__ cursor, int* __restrict__ payload, int relbit) {
    int e = blockIdx.x * blockDim.x + threadIdx.x;
    if (e < NE) {
        int d = dst[e];
        int pos = atomicAdd(cursor + d, 1);
        payload[pos] = src[e] | relbit;
    }
}

// ---------------- wave-per-dst aggregation, online softmax in registers ----
// lane = h*32+d. Per dst: qt_rel = Wk_rel . q (via shfl); per edge: gather raw
// k,v (256B each), 32-lane dot -> logit, online softmax; per-relation raw-v
// accumulators; epilogue applies Wv_w/Wv_c and writes normalized agg.
__global__ void csr_agg(const float* __restrict__ kqvp, const float* __restrict__ kqva,
                        const int* __restrict__ row_ptr, const int* __restrict__ deg,
                        const int* __restrict__ payload,
                        const float* __restrict__ Wk_w, const float* __restrict__ Wk_c,
                        const float* __restrict__ Wv_w, const float* __restrict__ Wv_c,
                        const float* __restrict__ p_w, const float* __restrict__ p_c,
                        float* __restrict__ agg) {
    __shared__ float WkTw[2048], WkTc[2048], Wvw[2048], Wvc[2048];
    for (int i = threadIdx.x; i < 2048; i += blockDim.x) {
        int h = i >> 10, dsrc = (i >> 5) & 31, f = i & 31;
        WkTw[(h << 10) | (f << 5) | dsrc] = Wk_w[i];  // transposed: [h][f][d]
        WkTc[(h << 10) | (f << 5) | dsrc] = Wk_c[i];
        Wvw[i] = Wv_w[i];                             // natural: [h][d][f]
        Wvc[i] = Wv_c[i];
    }
    __syncthreads();
    const int lane = threadIdx.x & 63;
    const int d = lane & 31;
    const int hb = lane & 32;              // h*32
    const int h = lane >> 5;
    const float rsq = 0.1767766952966369f;  // 1/sqrt(32)
    const float scw = p_w[h] * rsq, scc = p_c[h] * rsq;
    int wave_id = (blockIdx.x * blockDim.x + threadIdx.x) >> 6;
    int nwaves = (gridDim.x * blockDim.x) >> 6;
    for (int n = wave_id; n < NP; n += nwaves) {
        float qv = kqvp[(size_t)n * KQV + 64 + lane];  // q[h][d]
        float qtw = 0.f, qtc = 0.f;
#pragma unroll
        for (int f = 0; f < 32; ++f) {
            float qf = __shfl(qv, hb + f, 64);
            qtw = fmaf(qf, WkTw[(hb << 5) + (f << 5) + d], qtw);
            qtc = fmaf(qf, WkTc[(hb << 5) + (f << 5) + d], qtc);
        }
        int start = row_ptr[n], dg = deg[n];
        float m = -INFINITY, s = 0.f, accW = 0.f, accC = 0.f;
        for (int j = 0; j < dg; ++j) {
            int pl = payload[start + j];
            int rel = pl >> 30;
            int sn = pl & 0x3FFFFFFF;
            const float* base = rel ? (kqvp + (size_t)sn * KQV) : (kqva + (size_t)sn * 128);
            float kv = base[lane];                       // raw k[h][d]
            float vv = base[(rel ? 128 : 64) + lane];    // raw v[h][d]
            float prod = (rel ? qtc : qtw) * kv;
#pragma unroll
            for (int off = 1; off < 32; off <<= 1) prod += __shfl_xor(prod, off, 64);
            float l = prod * (rel ? scc : scw);
            if (l > m) {
                float r = __expf(m - l);   // m=-inf -> 0 -> zeroes (s,acc already 0)
                s *= r; accW *= r; accC *= r; m = l;
            }
            float ev = __expf(l - m);
            s += ev;
            if (rel) accC = fmaf(ev, vv, accC);
            else     accW = fmaf(ev, vv, accW);
        }
        float inv = 1.f / fmaxf(s, 1e-16f);
        float aw = accW * inv, ac = accC * inv;
        float out = 0.f;
#pragma unroll
        for (int dd = 0; dd < 32; ++dd) {
            float a1 = __shfl(aw, hb + dd, 64);
            float a2 = __shfl(ac, hb + dd, 64);
            out = fmaf(a1, Wvw[(hb << 5) + (dd << 5) + d], out);
            out = fmaf(a2, Wvc[(hb << 5) + (dd << 5) + d], out);
        }
        agg[(size_t)n * FF + lane] = out;
    }
}

// ---------------- epilogue ----------------
__global__ void finalize_k(const float* __restrict__ agg, const float* __restrict__ xp,
                           const float* __restrict__ aW, const float* __restrict__ ab,
                           const float* __restrict__ skip,
                           const float* __restrict__ outW, const float* __restrict__ outb,
                           float* __restrict__ out) {
    __shared__ float As[FF * FF];
    __shared__ float oWs[FF];
    __shared__ float Gs[4][FF];
    for (int i = threadIdx.x; i < FF * FF; i += blockDim.x) As[i] = aW[i];
    if (threadIdx.x < FF) oWs[threadIdx.x] = outW[threadIdx.x];
    __syncthreads();
    float sp = 1.f / (1.f + expf(-skip[0]));
    float ob = outb[0];
    int lane = threadIdx.x & 63;
    int rloc = threadIdx.x >> 6;
    float abv = ab[lane];
    for (int base = blockIdx.x * 4; base < NP; base += gridDim.x * 4) {
        int row = base + rloc;
        __syncthreads();
        if (row < NP) {
            float a = agg[(size_t)row * FF + lane];
            Gs[rloc][lane] = 0.5f * a * (1.f + erff(a * 0.7071067811865476f));
        }
        __syncthreads();
        if (row < NP) {
            float acc = abv;
#pragma unroll 8
            for (int c = 0; c < FF; ++c) acc = fmaf(Gs[rloc][c], As[c * FF + lane], acc);
            float hp = sp * acc + (1.f - sp) * xp[(size_t)row * FF + lane];
            float t = hp * oWs[lane];
#pragma unroll
            for (int off = 32; off > 0; off >>= 1) t += __shfl_down(t, off, 64);
            if (lane == 0) out[row] = t + ob;
        }
    }
}

extern "C" void kernel_launch(void* const* d_in, const int* in_sizes, int n_in,
                              void* d_out, int out_size, void* d_ws, size_t ws_size,
                              hipStream_t stream) {
    const float* x_paper  = (const float*)d_in[0];
    const float* x_author = (const float*)d_in[1];
    const int*   w_src    = (const int*)d_in[2];
    const int*   w_dst    = (const int*)d_in[3];
    const int*   c_src    = (const int*)d_in[4];
    const int*   c_dst    = (const int*)d_in[5];
    const float* linWp = (const float*)d_in[8];
    const float* linbp = (const float*)d_in[9];
    const float* linWa = (const float*)d_in[10];
    const float* linba = (const float*)d_in[11];
    const float* kqvWp = (const float*)d_in[12];
    const float* kqvbp = (const float*)d_in[13];
    const float* kqvWa = (const float*)d_in[14];
    const float* kqvba = (const float*)d_in[15];
    const float* aWp   = (const float*)d_in[16];
    const float* abp   = (const float*)d_in[17];
    const float* skipp = (const float*)d_in[20];
    const float* Wk_w  = (const float*)d_in[22];
    const float* Wv_w  = (const float*)d_in[23];
    const float* p_w   = (const float*)d_in[24];
    const float* Wk_c  = (const float*)d_in[25];
    const float* Wv_c  = (const float*)d_in[26];
    const float* p_c   = (const float*)d_in[27];
    const float* outW  = (const float*)d_in[31];
    const float* outb  = (const float*)d_in[32];
    float* out = (float*)d_out;

    // workspace layout
    float* ws   = (float*)d_ws;
    float* xp   = ws;                            // NP*64
    float* xa   = xp + (size_t)NP * FF;          // NA*64
    float* kqvp = xa + (size_t)NA * FF;          // NP*192
    float* kqva = kqvp + (size_t)NP * KQV;       // NA*128 (k|v)
    float* agg  = kqva + (size_t)NA * 128;       // NP*64
    int* deg     = (int*)(agg + (size_t)NP * FF); // NP
    int* row_ptr = deg + NP;                      // NP
    int* cursor  = row_ptr + NP;                  // NP
    int* bsum    = cursor + NP;                   // 1024
    int* payload = bsum + 1024;                   // 2*NE
    // total ~338 MB

    hipMemsetAsync(deg, 0, (size_t)NP * sizeof(int), stream);

    dim3 blk(256);
    const int NB = (NP + 255) / 256;  // 782

    lin_kernel<INDIM, FF, true><<<2048, blk, 0, stream>>>(x_paper, linWp, linbp, xp, NP);
    lin_kernel<INDIM, FF, true><<<2048, blk, 0, stream>>>(x_author, linWa, linba, xa, NA);
    lin_kernel<FF, KQV, false><<<2048, blk, 0, stream>>>(xp, kqvWp, kqvbp, kqvp, NP);
    lin_kv_kernel<<<2048, blk, 0, stream>>>(xa, kqvWa, kqvba, kqva, NA);

    deg_count<<<(2 * NE + 255) / 256, blk, 0, stream>>>(w_dst, c_dst, deg);
    scan_bsum<<<NB, blk, 0, stream>>>(deg, bsum, NP);
    scan_mid<<<1, blk, 0, stream>>>(bsum, NB);
    scan_final<<<NB, blk, 0, stream>>>(deg, bsum, row_ptr, cursor, NP);
    scatter_edges<<<(NE + 255) / 256, blk, 0, stream>>>(w_src, w_dst, cursor, payload, 0);
    scatter_edges<<<(NE + 255) / 256, blk, 0, stream>>>(c_src, c_dst, cursor, payload, 1 << 30);

    csr_agg<<<2048, blk, 0, stream>>>(kqvp, kqva, row_ptr, deg, payload,
                                      Wk_w, Wk_c, Wv_w, Wv_c, p_w, p_c, agg);

    finalize_k<<<2048, blk, 0, stream>>>(agg, xp, aWp, abp, skipp, outW, outb, out);
}

// Round 4
// 1084.635 us; speedup vs baseline: 3.6560x; 1.8414x over previous
//
#include <hip/hip_runtime.h>

#define NP 200000
#define NA 100000
#define NE 400000
#define HH 2
#define DD 32
#define FF 64
#define INDIM 128

// ---------------- dense linears (known-good) ----------------
// Y = act(X @ W + b), X:[N,FIN], W:[FIN,FOUT], 256 threads, 4 rows/iter,
// lane = output column (FOUT/64 cols per thread). W staged in LDS.
template <int FIN, int FOUT, bool RELU>
__global__ void lin_kernel(const float* __restrict__ X, const float* __restrict__ W,
                           const float* __restrict__ b, float* __restrict__ Y, int N) {
    __shared__ float Ws[FIN * FOUT];
    __shared__ float Xs[4][FIN];
    for (int i = threadIdx.x; i < FIN * FOUT; i += blockDim.x) Ws[i] = W[i];
    const int lane = threadIdx.x & 63;
    const int rloc = threadIdx.x >> 6;
    float breg[FOUT / 64];
#pragma unroll
    for (int j = 0; j < FOUT / 64; ++j) breg[j] = b[lane + 64 * j];
    __syncthreads();
    for (int base = blockIdx.x * 4; base < N; base += gridDim.x * 4) {
        __syncthreads();
        for (int i = threadIdx.x; i < 4 * FIN; i += blockDim.x) {
            int r = base + i / FIN;
            Xs[i / FIN][i % FIN] = (r < N) ? X[(size_t)r * FIN + (i % FIN)] : 0.f;
        }
        __syncthreads();
        int row = base + rloc;
        if (row < N) {
            float acc[FOUT / 64];
#pragma unroll
            for (int j = 0; j < FOUT / 64; ++j) acc[j] = breg[j];
            for (int i = 0; i < FIN; ++i) {
                float xv = Xs[rloc][i];
#pragma unroll
                for (int j = 0; j < FOUT / 64; ++j)
                    acc[j] = fmaf(xv, Ws[i * FOUT + lane + 64 * j], acc[j]);
            }
#pragma unroll
            for (int j = 0; j < FOUT / 64; ++j) {
                float v = acc[j];
                if (RELU) v = fmaxf(v, 0.f);
                Y[(size_t)row * FOUT + lane + 64 * j] = v;
            }
        }
    }
}

// ---------------- weight folding ----------------
// Paper rows (src of 'cites', dst q): 192 cols = [ (k'_0,v'_0)...(k'_63,v'_63) | q_0..q_63 ]
//   k'_{h,f} = sum_d k_{h,d} Wk_c[h][d][f] * p_c[h]/sqrt(D)
//   v'_{h,f} = sum_d v_{h,d} Wv_c[h][d][f]
// built as a column transform of kqv_W_paper (k block cols 0..63, q 64..127, v 128..191).
__global__ void fold_paper(const float* __restrict__ kqvW, const float* __restrict__ kqvb,
                           const float* __restrict__ Wk, const float* __restrict__ Wv,
                           const float* __restrict__ p,
                           float* __restrict__ Wt, float* __restrict__ bt) {
    int c = blockIdx.x;   // 0..191 output col
    int i = threadIdx.x;  // 0..63 input row
    const float rsq = 0.1767766952966369f;  // 1/sqrt(32)
    if (c < 128) {
        int m = c >> 1, h = m >> 5, f = m & 31;
        bool isK = (c & 1) == 0;
        const float* M = isK ? Wk : Wv;
        float sc = isK ? p[h] * rsq : 1.f;
        int srcbase = (isK ? 0 : 128) + h * 32;
        float acc = 0.f;
        for (int d = 0; d < 32; ++d)
            acc += kqvW[i * 192 + srcbase + d] * M[(h * 32 + d) * 32 + f];
        Wt[i * 192 + c] = acc * sc;
        if (i == 0) {
            float bb = 0.f;
            for (int d = 0; d < 32; ++d)
                bb += kqvb[srcbase + d] * M[(h * 32 + d) * 32 + f];
            bt[c] = bb * sc;
        }
    } else {
        Wt[i * 192 + c] = kqvW[i * 192 + 64 + (c - 128)];
        if (i == 0) bt[c] = kqvb[64 + (c - 128)];
    }
}

// Author rows (src of 'writes'): 128 cols = [ (k'_0,v'_0)...(k'_63,v'_63) ] with Wk_w/Wv_w.
__global__ void fold_author(const float* __restrict__ kqvW, const float* __restrict__ kqvb,
                            const float* __restrict__ Wk, const float* __restrict__ Wv,
                            const float* __restrict__ p,
                            float* __restrict__ Wt, float* __restrict__ bt) {
    int c = blockIdx.x;   // 0..127
    int i = threadIdx.x;  // 0..63
    const float rsq = 0.1767766952966369f;
    int m = c >> 1, h = m >> 5, f = m & 31;
    bool isK = (c & 1) == 0;
    const float* M = isK ? Wk : Wv;
    float sc = isK ? p[h] * rsq : 1.f;
    int srcbase = (isK ? 0 : 128) + h * 32;
    float acc = 0.f;
    for (int d = 0; d < 32; ++d)
        acc += kqvW[i * 192 + srcbase + d] * M[(h * 32 + d) * 32 + f];
    Wt[i * 128 + c] = acc * sc;
    if (i == 0) {
        float bb = 0.f;
        for (int d = 0; d < 32; ++d)
            bb += kqvb[srcbase + d] * M[(h * 32 + d) * 32 + f];
        bt[c] = bb * sc;
    }
}

// ---------------- CSR build ----------------
__global__ void deg_count(const int* __restrict__ d1, const int* __restrict__ d2,
                          int* __restrict__ deg) {
    int i = blockIdx.x * blockDim.x + threadIdx.x;
    if (i < 2 * NE) {
        int d = (i < NE) ? d1[i] : d2[i - NE];
        atomicAdd(deg + d, 1);
    }
}

__device__ __forceinline__ int block_excl_scan_256(int v) {
    __shared__ int wsum[4];
    int lane = threadIdx.x & 63, wv = threadIdx.x >> 6;
    int incl = v;
#pragma unroll
    for (int off = 1; off < 64; off <<= 1) {
        int t = __shfl_up(incl, off, 64);
        if (lane >= off) incl += t;
    }
    if (lane == 63) wsum[wv] = incl;
    __syncthreads();
    int wo = 0;
#pragma unroll
    for (int k = 0; k < 4; ++k) wo += (k < wv) ? wsum[k] : 0;
    __syncthreads();
    return wo + incl - v;
}

__global__ void scan_bsum(const int* __restrict__ deg, int* __restrict__ bsum, int n) {
    __shared__ int wsum[4];
    int i = blockIdx.x * 256 + threadIdx.x;
    int v = (i < n) ? deg[i] : 0;
#pragma unroll
    for (int off = 32; off > 0; off >>= 1) v += __shfl_xor(v, off, 64);
    int lane = threadIdx.x & 63, wv = threadIdx.x >> 6;
    if (lane == 0) wsum[wv] = v;
    __syncthreads();
    if (threadIdx.x == 0) bsum[blockIdx.x] = wsum[0] + wsum[1] + wsum[2] + wsum[3];
}

__global__ void scan_mid(int* __restrict__ bsum, int nb) {
    __shared__ int carry;
    if (threadIdx.x == 0) carry = 0;
    __syncthreads();
    for (int base = 0; base < nb; base += 256) {
        int i = base + threadIdx.x;
        int v = (i < nb) ? bsum[i] : 0;
        int ex = block_excl_scan_256(v);
        int c = carry;
        __syncthreads();
        if (i < nb) bsum[i] = ex + c;
        if (threadIdx.x == 255) carry = c + ex + v;
        __syncthreads();
    }
}

__global__ void scan_final(const int* __restrict__ deg, const int* __restrict__ bsum,
                           int* __restrict__ row_ptr, int* __restrict__ cursor, int n) {
    int i = blockIdx.x * 256 + threadIdx.x;
    int v = (i < n) ? deg[i] : 0;
    int ex = block_excl_scan_256(v) + bsum[blockIdx.x];
    if (i < n) { row_ptr[i] = ex; cursor[i] = ex; }
}

__global__ void scatter_edges(const int* __restrict__ src, const int* __restrict__ dst,
                              int* __restrict__ cursor, int* __restrict__ payload, int relbit) {
    int e = blockIdx.x * blockDim.x + threadIdx.x;
    if (e < NE) {
        int d = dst[e];
        int pos = atomicAdd(cursor + d, 1);
        payload[pos] = src[e] | relbit;
    }
}

// ---------------- wave-per-dst aggregation, branch-free, unroll-4 ----------
// lane = h*32+f. Per edge: one float2 gather (k'[lane], v'[lane]) -> dot with
// raw q (per-head 32-lane xor reduce) -> exp -> accumulate. Softmax without
// max-subtraction (|logit| << 80, shift-invariant). agg written normalized.
__global__ void csr_agg(const float* __restrict__ pG, const float* __restrict__ aG,
                        const int* __restrict__ row_ptr, const int* __restrict__ deg,
                        const int* __restrict__ payload, float* __restrict__ agg) {
    const int lane = threadIdx.x & 63;
    int wave_id = (blockIdx.x * blockDim.x + threadIdx.x) >> 6;
    int nwaves = (gridDim.x * blockDim.x) >> 6;
    for (int n = wave_id; n < NP; n += nwaves) {
        float q_l = pG[(size_t)n * 192 + 128 + lane];
        int start = row_ptr[n], dg = deg[n];
        float s = 0.f, acc = 0.f;
        for (int j = 0; j < dg; j += 4) {
            float kvx[4], vvy[4], msk[4];
#pragma unroll
            for (int c = 0; c < 4; ++c) {
                int jj = j + c;
                bool ok = jj < dg;
                int pl = payload[start + (ok ? jj : 0)];
                int rel = (int)((unsigned)pl >> 30);
                int sn = pl & 0x3FFFFFFF;
                const float* base = rel ? (pG + (size_t)sn * 192) : (aG + (size_t)sn * 128);
                float2 t = *(const float2*)(base + 2 * lane);
                kvx[c] = t.x;
                vvy[c] = t.y;
                msk[c] = ok ? 1.f : 0.f;
            }
#pragma unroll
            for (int c = 0; c < 4; ++c) {
                float prod = q_l * kvx[c];
#pragma unroll
                for (int off = 1; off < 32; off <<= 1) prod += __shfl_xor(prod, off, 64);
                float e = __expf(prod) * msk[c];
                s += e;
                acc = fmaf(e, vvy[c], acc);
            }
        }
        float inv = 1.f / fmaxf(s, 1e-16f);
        agg[(size_t)n * FF + lane] = acc * inv;
    }
}

// ---------------- epilogue ----------------
__global__ void finalize_k(const float* __restrict__ agg, const float* __restrict__ xp,
                           const float* __restrict__ aW, const float* __restrict__ ab,
                           const float* __restrict__ skip,
                           const float* __restrict__ outW, const float* __restrict__ outb,
                           float* __restrict__ out) {
    __shared__ float As[FF * FF];
    __shared__ float oWs[FF];
    __shared__ float Gs[4][FF];
    for (int i = threadIdx.x; i < FF * FF; i += blockDim.x) As[i] = aW[i];
    if (threadIdx.x < FF) oWs[threadIdx.x] = outW[threadIdx.x];
    __syncthreads();
    float sp = 1.f / (1.f + expf(-skip[0]));
    float ob = outb[0];
    int lane = threadIdx.x & 63;
    int rloc = threadIdx.x >> 6;
    float abv = ab[lane];
    for (int base = blockIdx.x * 4; base < NP; base += gridDim.x * 4) {
        int row = base + rloc;
        __syncthreads();
        if (row < NP) {
            float a = agg[(size_t)row * FF + lane];
            Gs[rloc][lane] = 0.5f * a * (1.f + erff(a * 0.7071067811865476f));
        }
        __syncthreads();
        if (row < NP) {
            float acc = abv;
#pragma unroll 8
            for (int c = 0; c < FF; ++c) acc = fmaf(Gs[rloc][c], As[c * FF + lane], acc);
            float hp = sp * acc + (1.f - sp) * xp[(size_t)row * FF + lane];
            float t = hp * oWs[lane];
#pragma unroll
            for (int off = 32; off > 0; off >>= 1) t += __shfl_down(t, off, 64);
            if (lane == 0) out[row] = t + ob;
        }
    }
}

extern "C" void kernel_launch(void* const* d_in, const int* in_sizes, int n_in,
                              void* d_out, int out_size, void* d_ws, size_t ws_size,
                              hipStream_t stream) {
    const float* x_paper  = (const float*)d_in[0];
    const float* x_author = (const float*)d_in[1];
    const int*   w_src    = (const int*)d_in[2];
    const int*   w_dst    = (const int*)d_in[3];
    const int*   c_src    = (const int*)d_in[4];
    const int*   c_dst    = (const int*)d_in[5];
    const float* linWp = (const float*)d_in[8];
    const float* linbp = (const float*)d_in[9];
    const float* linWa = (const float*)d_in[10];
    const float* linba = (const float*)d_in[11];
    const float* kqvWp = (const float*)d_in[12];
    const float* kqvbp = (const float*)d_in[13];
    const float* kqvWa = (const float*)d_in[14];
    const float* kqvba = (const float*)d_in[15];
    const float* aWp   = (const float*)d_in[16];
    const float* abp   = (const float*)d_in[17];
    const float* skipp = (const float*)d_in[20];
    const float* Wk_w  = (const float*)d_in[22];
    const float* Wv_w  = (const float*)d_in[23];
    const float* p_w   = (const float*)d_in[24];
    const float* Wk_c  = (const float*)d_in[25];
    const float* Wv_c  = (const float*)d_in[26];
    const float* p_c   = (const float*)d_in[27];
    const float* outW  = (const float*)d_in[31];
    const float* outb  = (const float*)d_in[32];
    float* out = (float*)d_out;

    // workspace layout (floats) — ~339 MB total (<= 366 MB proven in round 1)
    float* ws   = (float*)d_ws;
    float* xp   = ws;                            // NP*64
    float* xa   = xp + (size_t)NP * FF;          // NA*64
    float* pG   = xa + (size_t)NA * FF;          // NP*192  [kv-interleaved | q]
    float* aG   = pG + (size_t)NP * 192;         // NA*128  [kv-interleaved]
    float* agg  = aG + (size_t)NA * 128;         // NP*64
    float* WtP  = agg + (size_t)NP * FF;         // 64*192
    float* btP  = WtP + 64 * 192;                // 192
    float* WtA  = btP + 192;                     // 64*128
    float* btA  = WtA + 64 * 128;                // 128
    int* deg     = (int*)(btA + 128);            // NP
    int* row_ptr = deg + NP;                     // NP
    int* cursor  = row_ptr + NP;                 // NP
    int* bsum    = cursor + NP;                  // 1024
    int* payload = bsum + 1024;                  // 2*NE

    hipMemsetAsync(deg, 0, (size_t)NP * sizeof(int), stream);

    dim3 blk(256);
    const int NB = (NP + 255) / 256;  // 782

    // fold relation matrices into projection weights (tiny)
    fold_paper<<<192, 64, 0, stream>>>(kqvWp, kqvbp, Wk_c, Wv_c, p_c, WtP, btP);
    fold_author<<<128, 64, 0, stream>>>(kqvWa, kqvba, Wk_w, Wv_w, p_w, WtA, btA);

    lin_kernel<INDIM, FF, true><<<2048, blk, 0, stream>>>(x_paper, linWp, linbp, xp, NP);
    lin_kernel<INDIM, FF, true><<<2048, blk, 0, stream>>>(x_author, linWa, linba, xa, NA);
    lin_kernel<FF, 192, false><<<2048, blk, 0, stream>>>(xp, WtP, btP, pG, NP);
    lin_kernel<FF, 128, false><<<2048, blk, 0, stream>>>(xa, WtA, btA, aG, NA);

    deg_count<<<(2 * NE + 255) / 256, blk, 0, stream>>>(w_dst, c_dst, deg);
    scan_bsum<<<NB, blk, 0, stream>>>(deg, bsum, NP);
    scan_mid<<<1, blk, 0, stream>>>(bsum, NB);
    scan_final<<<NB, blk, 0, stream>>>(deg, bsum, row_ptr, cursor, NP);
    scatter_edges<<<(NE + 255) / 256, blk, 0, stream>>>(w_src, w_dst, cursor, payload, 0);
    scatter_edges<<<(NE + 255) / 256, blk, 0, stream>>>(c_src, c_dst, cursor, payload, 1 << 30);

    csr_agg<<<4096, blk, 0, stream>>>(pG, aG, row_ptr, deg, payload, agg);

    finalize_k<<<2048, blk, 0, stream>>>(agg, xp, aWp, abp, skipp, outW, outb, out);
}

// Round 5
// 765.369 us; speedup vs baseline: 5.1811x; 1.4171x over previous
//
#include <hip/hip_runtime.h>

#define NP 200000
#define NA 100000
#define NE 400000
#define HH 2
#define DD 32
#define FF 64
#define INDIM 128

// ---------------- register-blocked fp32 linear ----------------
// Y = act(X @ W + b). 256 threads = 16(ty) x 16(tx); each thread computes a
// 4-row x 4-col x CT block. W staged once per block in LDS; X tiles (64 rows)
// staged row-major padded. Inner loop: k step 4 -> 4 X b128 (broadcast) +
// 4*CT W b128 reads, 64*CT FMAs.
template <int FIN, int FOUT, bool RELU>
__global__ __launch_bounds__(256) void lin2_kernel(const float* __restrict__ X,
                                                   const float* __restrict__ W,
                                                   const float* __restrict__ b,
                                                   float* __restrict__ Y, int N) {
    constexpr int CT = FOUT / 64;
    constexpr int XP = FIN + 4;  // padded X row stride (floats), mult of 4
    __shared__ float Ws[FIN * FOUT];
    __shared__ float Xs[64 * XP];
    for (int i = threadIdx.x; i < FIN * FOUT / 4; i += 256)
        ((float4*)Ws)[i] = ((const float4*)W)[i];
    const int ty = threadIdx.x >> 4;
    const int tx = threadIdx.x & 15;
    const int c0 = tx * 4;
    float4 breg[CT];
#pragma unroll
    for (int ct = 0; ct < CT; ++ct) breg[ct] = *(const float4*)(b + ct * 64 + c0);
    const int ntiles = (N + 63) >> 6;
    for (int tile = blockIdx.x; tile < ntiles; tile += gridDim.x) {
        const int base = tile << 6;
        __syncthreads();
        for (int i = threadIdx.x; i < 64 * FIN / 4; i += 256) {
            int r = i / (FIN / 4);
            int k4 = (i % (FIN / 4)) * 4;
            int row = base + r;
            if (row >= N) row = N - 1;
            *(float4*)(Xs + r * XP + k4) = *(const float4*)(X + (size_t)row * FIN + k4);
        }
        __syncthreads();
        float acc[4][4 * CT];
#pragma unroll
        for (int j = 0; j < 4; ++j)
#pragma unroll
            for (int ct = 0; ct < CT; ++ct) {
                acc[j][ct * 4 + 0] = breg[ct].x;
                acc[j][ct * 4 + 1] = breg[ct].y;
                acc[j][ct * 4 + 2] = breg[ct].z;
                acc[j][ct * 4 + 3] = breg[ct].w;
            }
        for (int k4 = 0; k4 < FIN; k4 += 4) {
            float4 xr[4];
#pragma unroll
            for (int j = 0; j < 4; ++j)
                xr[j] = *(const float4*)(Xs + (ty * 4 + j) * XP + k4);
            float4 wv[4][CT];
#pragma unroll
            for (int kk = 0; kk < 4; ++kk)
#pragma unroll
                for (int ct = 0; ct < CT; ++ct)
                    wv[kk][ct] = *(const float4*)(Ws + (k4 + kk) * FOUT + ct * 64 + c0);
#pragma unroll
            for (int kk = 0; kk < 4; ++kk) {
#pragma unroll
                for (int j = 0; j < 4; ++j) {
                    float xk[4] = {xr[j].x, xr[j].y, xr[j].z, xr[j].w};
                    float xv = xk[kk];
#pragma unroll
                    for (int ct = 0; ct < CT; ++ct) {
                        acc[j][ct * 4 + 0] = fmaf(xv, wv[kk][ct].x, acc[j][ct * 4 + 0]);
                        acc[j][ct * 4 + 1] = fmaf(xv, wv[kk][ct].y, acc[j][ct * 4 + 1]);
                        acc[j][ct * 4 + 2] = fmaf(xv, wv[kk][ct].z, acc[j][ct * 4 + 2]);
                        acc[j][ct * 4 + 3] = fmaf(xv, wv[kk][ct].w, acc[j][ct * 4 + 3]);
                    }
                }
            }
        }
#pragma unroll
        for (int j = 0; j < 4; ++j) {
            int row = base + ty * 4 + j;
            if (row < N) {
#pragma unroll
                for (int ct = 0; ct < CT; ++ct) {
                    float4 o;
                    o.x = acc[j][ct * 4 + 0]; o.y = acc[j][ct * 4 + 1];
                    o.z = acc[j][ct * 4 + 2]; o.w = acc[j][ct * 4 + 3];
                    if (RELU) {
                        o.x = fmaxf(o.x, 0.f); o.y = fmaxf(o.y, 0.f);
                        o.z = fmaxf(o.z, 0.f); o.w = fmaxf(o.w, 0.f);
                    }
                    *(float4*)(Y + (size_t)row * FOUT + ct * 64 + c0) = o;
                }
            }
        }
    }
}

// ---------------- weight folding (known-good) ----------------
__global__ void fold_paper(const float* __restrict__ kqvW, const float* __restrict__ kqvb,
                           const float* __restrict__ Wk, const float* __restrict__ Wv,
                           const float* __restrict__ p,
                           float* __restrict__ Wt, float* __restrict__ bt) {
    int c = blockIdx.x;
    int i = threadIdx.x;
    const float rsq = 0.1767766952966369f;
    if (c < 128) {
        int m = c >> 1, h = m >> 5, f = m & 31;
        bool isK = (c & 1) == 0;
        const float* M = isK ? Wk : Wv;
        float sc = isK ? p[h] * rsq : 1.f;
        int srcbase = (isK ? 0 : 128) + h * 32;
        float acc = 0.f;
        for (int d = 0; d < 32; ++d)
            acc += kqvW[i * 192 + srcbase + d] * M[(h * 32 + d) * 32 + f];
        Wt[i * 192 + c] = acc * sc;
        if (i == 0) {
            float bb = 0.f;
            for (int d = 0; d < 32; ++d)
                bb += kqvb[srcbase + d] * M[(h * 32 + d) * 32 + f];
            bt[c] = bb * sc;
        }
    } else {
        Wt[i * 192 + c] = kqvW[i * 192 + 64 + (c - 128)];
        if (i == 0) bt[c] = kqvb[64 + (c - 128)];
    }
}

__global__ void fold_author(const float* __restrict__ kqvW, const float* __restrict__ kqvb,
                            const float* __restrict__ Wk, const float* __restrict__ Wv,
                            const float* __restrict__ p,
                            float* __restrict__ Wt, float* __restrict__ bt) {
    int c = blockIdx.x;
    int i = threadIdx.x;
    const float rsq = 0.1767766952966369f;
    int m = c >> 1, h = m >> 5, f = m & 31;
    bool isK = (c & 1) == 0;
    const float* M = isK ? Wk : Wv;
    float sc = isK ? p[h] * rsq : 1.f;
    int srcbase = (isK ? 0 : 128) + h * 32;
    float acc = 0.f;
    for (int d = 0; d < 32; ++d)
        acc += kqvW[i * 192 + srcbase + d] * M[(h * 32 + d) * 32 + f];
    Wt[i * 128 + c] = acc * sc;
    if (i == 0) {
        float bb = 0.f;
        for (int d = 0; d < 32; ++d)
            bb += kqvb[srcbase + d] * M[(h * 32 + d) * 32 + f];
        bt[c] = bb * sc;
    }
}

// ---------------- CSR build (known-good) ----------------
__global__ void deg_count(const int* __restrict__ d1, const int* __restrict__ d2,
                          int* __restrict__ deg) {
    int i = blockIdx.x * blockDim.x + threadIdx.x;
    if (i < 2 * NE) {
        int d = (i < NE) ? d1[i] : d2[i - NE];
        atomicAdd(deg + d, 1);
    }
}

__device__ __forceinline__ int block_excl_scan_256(int v) {
    __shared__ int wsum[4];
    int lane = threadIdx.x & 63, wv = threadIdx.x >> 6;
    int incl = v;
#pragma unroll
    for (int off = 1; off < 64; off <<= 1) {
        int t = __shfl_up(incl, off, 64);
        if (lane >= off) incl += t;
    }
    if (lane == 63) wsum[wv] = incl;
    __syncthreads();
    int wo = 0;
#pragma unroll
    for (int k = 0; k < 4; ++k) wo += (k < wv) ? wsum[k] : 0;
    __syncthreads();
    return wo + incl - v;
}

__global__ void scan_bsum(const int* __restrict__ deg, int* __restrict__ bsum, int n) {
    __shared__ int wsum[4];
    int i = blockIdx.x * 256 + threadIdx.x;
    int v = (i < n) ? deg[i] : 0;
#pragma unroll
    for (int off = 32; off > 0; off >>= 1) v += __shfl_xor(v, off, 64);
    int lane = threadIdx.x & 63, wv = threadIdx.x >> 6;
    if (lane == 0) wsum[wv] = v;
    __syncthreads();
    if (threadIdx.x == 0) bsum[blockIdx.x] = wsum[0] + wsum[1] + wsum[2] + wsum[3];
}

__global__ void scan_mid(int* __restrict__ bsum, int nb) {
    __shared__ int carry;
    if (threadIdx.x == 0) carry = 0;
    __syncthreads();
    for (int base = 0; base < nb; base += 256) {
        int i = base + threadIdx.x;
        int v = (i < nb) ? bsum[i] : 0;
        int ex = block_excl_scan_256(v);
        int c = carry;
        __syncthreads();
        if (i < nb) bsum[i] = ex + c;
        if (threadIdx.x == 255) carry = c + ex + v;
        __syncthreads();
    }
}

__global__ void scan_final(const int* __restrict__ deg, const int* __restrict__ bsum,
                           int* __restrict__ row_ptr, int* __restrict__ cursor, int n) {
    int i = blockIdx.x * 256 + threadIdx.x;
    int v = (i < n) ? deg[i] : 0;
    int ex = block_excl_scan_256(v) + bsum[blockIdx.x];
    if (i < n) { row_ptr[i] = ex; cursor[i] = ex; }
}

__global__ void scatter_edges(const int* __restrict__ src, const int* __restrict__ dst,
                              int* __restrict__ cursor, int* __restrict__ payload, int relbit) {
    int e = blockIdx.x * blockDim.x + threadIdx.x;
    if (e < NE) {
        int d = dst[e];
        int pos = atomicAdd(cursor + d, 1);
        payload[pos] = src[e] | relbit;
    }
}

// ---------------- wave-per-dst aggregation (known-good) ----------------
__global__ void csr_agg(const float* __restrict__ pG, const float* __restrict__ aG,
                        const int* __restrict__ row_ptr, const int* __restrict__ deg,
                        const int* __restrict__ payload, float* __restrict__ agg) {
    const int lane = threadIdx.x & 63;
    int wave_id = (blockIdx.x * blockDim.x + threadIdx.x) >> 6;
    int nwaves = (gridDim.x * blockDim.x) >> 6;
    for (int n = wave_id; n < NP; n += nwaves) {
        float q_l = pG[(size_t)n * 192 + 128 + lane];
        int start = row_ptr[n], dg = deg[n];
        float s = 0.f, acc = 0.f;
        for (int j = 0; j < dg; j += 4) {
            float kvx[4], vvy[4], msk[4];
#pragma unroll
            for (int c = 0; c < 4; ++c) {
                int jj = j + c;
                bool ok = jj < dg;
                int pl = payload[start + (ok ? jj : 0)];
                int rel = (int)((unsigned)pl >> 30);
                int sn = pl & 0x3FFFFFFF;
                const float* base = rel ? (pG + (size_t)sn * 192) : (aG + (size_t)sn * 128);
                float2 t = *(const float2*)(base + 2 * lane);
                kvx[c] = t.x;
                vvy[c] = t.y;
                msk[c] = ok ? 1.f : 0.f;
            }
#pragma unroll
            for (int c = 0; c < 4; ++c) {
                float prod = q_l * kvx[c];
#pragma unroll
                for (int off = 1; off < 32; off <<= 1) prod += __shfl_xor(prod, off, 64);
                float e = __expf(prod) * msk[c];
                s += e;
                acc = fmaf(e, vvy[c], acc);
            }
        }
        float inv = 1.f / fmaxf(s, 1e-16f);
        agg[(size_t)n * FF + lane] = acc * inv;
    }
}

// ---------------- fused epilogue (register-blocked) ----------------
// per 64-row tile: Gs = gelu(agg) staged; acc = Gs @ aW + ab (4x4/thread);
// hp = sp*acc + (1-sp)*xp; out = hp . outW (16-lane shfl reduce).
__global__ __launch_bounds__(256) void finalize2(const float* __restrict__ agg,
                                                 const float* __restrict__ xp,
                                                 const float* __restrict__ aW,
                                                 const float* __restrict__ ab,
                                                 const float* __restrict__ skip,
                                                 const float* __restrict__ outW,
                                                 const float* __restrict__ outb,
                                                 float* __restrict__ out) {
    __shared__ float As[64 * 64];
    __shared__ float Gs[64 * 68];
    for (int i = threadIdx.x; i < 64 * 64 / 4; i += 256)
        ((float4*)As)[i] = ((const float4*)aW)[i];
    const int ty = threadIdx.x >> 4;
    const int tx = threadIdx.x & 15;
    const int c0 = tx * 4;
    const float sp = 1.f / (1.f + expf(-skip[0]));
    const float ob = outb[0];
    float4 ab4 = *(const float4*)(ab + c0);
    float4 oW4 = *(const float4*)(outW + c0);
    const int ntiles = NP >> 6;  // 200000/64 = 3125 exact
    for (int tile = blockIdx.x; tile < ntiles; tile += gridDim.x) {
        const int base = tile << 6;
        __syncthreads();
        for (int i = threadIdx.x; i < 64 * 16; i += 256) {
            int r = i >> 4;
            int k4 = (i & 15) * 4;
            float4 v = *(const float4*)(agg + (size_t)(base + r) * 64 + k4);
            v.x = 0.5f * v.x * (1.f + erff(v.x * 0.7071067811865476f));
            v.y = 0.5f * v.y * (1.f + erff(v.y * 0.7071067811865476f));
            v.z = 0.5f * v.z * (1.f + erff(v.z * 0.7071067811865476f));
            v.w = 0.5f * v.w * (1.f + erff(v.w * 0.7071067811865476f));
            *(float4*)(Gs + r * 68 + k4) = v;
        }
        __syncthreads();
        float acc[4][4];
#pragma unroll
        for (int j = 0; j < 4; ++j) {
            acc[j][0] = ab4.x; acc[j][1] = ab4.y; acc[j][2] = ab4.z; acc[j][3] = ab4.w;
        }
        for (int k4 = 0; k4 < 64; k4 += 4) {
            float4 xr[4];
#pragma unroll
            for (int j = 0; j < 4; ++j)
                xr[j] = *(const float4*)(Gs + (ty * 4 + j) * 68 + k4);
            float4 wv[4];
#pragma unroll
            for (int kk = 0; kk < 4; ++kk)
                wv[kk] = *(const float4*)(As + (k4 + kk) * 64 + c0);
#pragma unroll
            for (int kk = 0; kk < 4; ++kk) {
#pragma unroll
                for (int j = 0; j < 4; ++j) {
                    float xk[4] = {xr[j].x, xr[j].y, xr[j].z, xr[j].w};
                    float xv = xk[kk];
                    acc[j][0] = fmaf(xv, wv[kk].x, acc[j][0]);
                    acc[j][1] = fmaf(xv, wv[kk].y, acc[j][1]);
                    acc[j][2] = fmaf(xv, wv[kk].z, acc[j][2]);
                    acc[j][3] = fmaf(xv, wv[kk].w, acc[j][3]);
                }
            }
        }
#pragma unroll
        for (int j = 0; j < 4; ++j) {
            int row = base + ty * 4 + j;
            float4 xv = *(const float4*)(xp + (size_t)row * 64 + c0);
            float t = (sp * acc[j][0] + (1.f - sp) * xv.x) * oW4.x;
            t = fmaf(sp * acc[j][1] + (1.f - sp) * xv.y, oW4.y, t);
            t = fmaf(sp * acc[j][2] + (1.f - sp) * xv.z, oW4.z, t);
            t = fmaf(sp * acc[j][3] + (1.f - sp) * xv.w, oW4.w, t);
#pragma unroll
            for (int off = 1; off < 16; off <<= 1) t += __shfl_xor(t, off, 64);
            if (tx == 0) out[row] = t + ob;
        }
    }
}

extern "C" void kernel_launch(void* const* d_in, const int* in_sizes, int n_in,
                              void* d_out, int out_size, void* d_ws, size_t ws_size,
                              hipStream_t stream) {
    const float* x_paper  = (const float*)d_in[0];
    const float* x_author = (const float*)d_in[1];
    const int*   w_src    = (const int*)d_in[2];
    const int*   w_dst    = (const int*)d_in[3];
    const int*   c_src    = (const int*)d_in[4];
    const int*   c_dst    = (const int*)d_in[5];
    const float* linWp = (const float*)d_in[8];
    const float* linbp = (const float*)d_in[9];
    const float* linWa = (const float*)d_in[10];
    const float* linba = (const float*)d_in[11];
    const float* kqvWp = (const float*)d_in[12];
    const float* kqvbp = (const float*)d_in[13];
    const float* kqvWa = (const float*)d_in[14];
    const float* kqvba = (const float*)d_in[15];
    const float* aWp   = (const float*)d_in[16];
    const float* abp   = (const float*)d_in[17];
    const float* skipp = (const float*)d_in[20];
    const float* Wk_w  = (const float*)d_in[22];
    const float* Wv_w  = (const float*)d_in[23];
    const float* p_w   = (const float*)d_in[24];
    const float* Wk_c  = (const float*)d_in[25];
    const float* Wv_c  = (const float*)d_in[26];
    const float* p_c   = (const float*)d_in[27];
    const float* outW  = (const float*)d_in[31];
    const float* outb  = (const float*)d_in[32];
    float* out = (float*)d_out;

    // workspace layout (floats) — ~339 MB
    float* ws   = (float*)d_ws;
    float* xp   = ws;                            // NP*64
    float* xa   = xp + (size_t)NP * FF;          // NA*64
    float* pG   = xa + (size_t)NA * FF;          // NP*192  [kv-interleaved | q]
    float* aG   = pG + (size_t)NP * 192;         // NA*128  [kv-interleaved]
    float* agg  = aG + (size_t)NA * 128;         // NP*64
    float* WtP  = agg + (size_t)NP * FF;         // 64*192
    float* btP  = WtP + 64 * 192;                // 192
    float* WtA  = btP + 192;                     // 64*128
    float* btA  = WtA + 64 * 128;                // 128
    int* deg     = (int*)(btA + 128);            // NP
    int* row_ptr = deg + NP;                     // NP
    int* cursor  = row_ptr + NP;                 // NP
    int* bsum    = cursor + NP;                  // 1024
    int* payload = bsum + 1024;                  // 2*NE

    hipMemsetAsync(deg, 0, (size_t)NP * sizeof(int), stream);

    dim3 blk(256);
    const int NB = (NP + 255) / 256;  // 782

    fold_paper<<<192, 64, 0, stream>>>(kqvWp, kqvbp, Wk_c, Wv_c, p_c, WtP, btP);
    fold_author<<<128, 64, 0, stream>>>(kqvWa, kqvba, Wk_w, Wv_w, p_w, WtA, btA);

    lin2_kernel<INDIM, FF, true><<<1024, blk, 0, stream>>>(x_paper, linWp, linbp, xp, NP);
    lin2_kernel<INDIM, FF, true><<<1024, blk, 0, stream>>>(x_author, linWa, linba, xa, NA);
    lin2_kernel<FF, 192, false><<<1024, blk, 0, stream>>>(xp, WtP, btP, pG, NP);
    lin2_kernel<FF, 128, false><<<1024, blk, 0, stream>>>(xa, WtA, btA, aG, NA);

    deg_count<<<(2 * NE + 255) / 256, blk, 0, stream>>>(w_dst, c_dst, deg);
    scan_bsum<<<NB, blk, 0, stream>>>(deg, bsum, NP);
    scan_mid<<<1, blk, 0, stream>>>(bsum, NB);
    scan_final<<<NB, blk, 0, stream>>>(deg, bsum, row_ptr, cursor, NP);
    scatter_edges<<<(NE + 255) / 256, blk, 0, stream>>>(w_src, w_dst, cursor, payload, 0);
    scatter_edges<<<(NE + 255) / 256, blk, 0, stream>>>(c_src, c_dst, cursor, payload, 1 << 30);

    csr_agg<<<4096, blk, 0, stream>>>(pG, aG, row_ptr, deg, payload, agg);

    finalize2<<<1024, blk, 0, stream>>>(agg, xp, aWp, abp, skipp, outW, outb, out);
}

// Round 11
// 674.023 us; speedup vs baseline: 5.8832x; 1.1355x over previous
//
#include <hip/hip_runtime.h>

#define NP 200000
#define NA 100000
#define NE 400000
#define HH 2
#define DD 32
#define FF 64
#define INDIM 128

// ---------------- register-blocked fp32 linear (device fn, shared blob) ----
// Y = act(X @ W + b). 256 threads = 16(ty) x 16(tx); each thread computes
// 4 rows x (4*CT) cols. W staged in LDS blob; X tiles (64 rows) padded.
// blob usage: Ws[FIN*FOUT] | Xs[64*(FIN+4)]  (max 16640 floats)
template <int FIN, int FOUT, bool RELU>
__device__ void lin2_dev(float* __restrict__ blob, const float* __restrict__ X,
                         const float* __restrict__ W, const float* __restrict__ b,
                         float* __restrict__ Y, int N, int bid, int nblocks) {
    constexpr int CT = FOUT / 64;
    constexpr int XP = FIN + 4;
    float* Ws = blob;
    float* Xs = blob + FIN * FOUT;
    for (int i = threadIdx.x; i < FIN * FOUT / 4; i += 256)
        ((float4*)Ws)[i] = ((const float4*)W)[i];
    const int ty = threadIdx.x >> 4;
    const int tx = threadIdx.x & 15;
    const int c0 = tx * 4;
    float4 breg[CT];
#pragma unroll
    for (int ct = 0; ct < CT; ++ct) breg[ct] = *(const float4*)(b + ct * 64 + c0);
    const int ntiles = (N + 63) >> 6;
    for (int tile = bid; tile < ntiles; tile += nblocks) {
        const int base = tile << 6;
        __syncthreads();
        for (int i = threadIdx.x; i < 64 * FIN / 4; i += 256) {
            int r = i / (FIN / 4);
            int k4 = (i % (FIN / 4)) * 4;
            int row = base + r;
            if (row >= N) row = N - 1;
            *(float4*)(Xs + r * XP + k4) = *(const float4*)(X + (size_t)row * FIN + k4);
        }
        __syncthreads();
        float acc[4][4 * CT];
#pragma unroll
        for (int j = 0; j < 4; ++j)
#pragma unroll
            for (int ct = 0; ct < CT; ++ct) {
                acc[j][ct * 4 + 0] = breg[ct].x;
                acc[j][ct * 4 + 1] = breg[ct].y;
                acc[j][ct * 4 + 2] = breg[ct].z;
                acc[j][ct * 4 + 3] = breg[ct].w;
            }
        for (int k4 = 0; k4 < FIN; k4 += 4) {
            float4 xr[4];
#pragma unroll
            for (int j = 0; j < 4; ++j)
                xr[j] = *(const float4*)(Xs + (ty * 4 + j) * XP + k4);
            float4 wv[4][CT];
#pragma unroll
            for (int kk = 0; kk < 4; ++kk)
#pragma unroll
                for (int ct = 0; ct < CT; ++ct)
                    wv[kk][ct] = *(const float4*)(Ws + (k4 + kk) * FOUT + ct * 64 + c0);
#pragma unroll
            for (int kk = 0; kk < 4; ++kk) {
#pragma unroll
                for (int j = 0; j < 4; ++j) {
                    float xk[4] = {xr[j].x, xr[j].y, xr[j].z, xr[j].w};
                    float xv = xk[kk];
#pragma unroll
                    for (int ct = 0; ct < CT; ++ct) {
                        acc[j][ct * 4 + 0] = fmaf(xv, wv[kk][ct].x, acc[j][ct * 4 + 0]);
                        acc[j][ct * 4 + 1] = fmaf(xv, wv[kk][ct].y, acc[j][ct * 4 + 1]);
                        acc[j][ct * 4 + 2] = fmaf(xv, wv[kk][ct].z, acc[j][ct * 4 + 2]);
                        acc[j][ct * 4 + 3] = fmaf(xv, wv[kk][ct].w, acc[j][ct * 4 + 3]);
                    }
                }
            }
        }
#pragma unroll
        for (int j = 0; j < 4; ++j) {
            int row = base + ty * 4 + j;
            if (row < N) {
#pragma unroll
                for (int ct = 0; ct < CT; ++ct) {
                    float4 o;
                    o.x = acc[j][ct * 4 + 0]; o.y = acc[j][ct * 4 + 1];
                    o.z = acc[j][ct * 4 + 2]; o.w = acc[j][ct * 4 + 3];
                    if (RELU) {
                        o.x = fmaxf(o.x, 0.f); o.y = fmaxf(o.y, 0.f);
                        o.z = fmaxf(o.z, 0.f); o.w = fmaxf(o.w, 0.f);
                    }
                    *(float4*)(Y + (size_t)row * FOUT + ct * 64 + c0) = o;
                }
            }
        }
    }
}

// ---------------- weight folding (device fns, pair-of-pairs layout) ----
// fragment float4 pi in [0,32): (k'_{h,f0}, v'_{h,f0}, k'_{h,f1}, v'_{h,f1}),
// h = pi>>4, f0 = (pi&15)*2, f1 = f0+1.  column c in [0,128):
// pi=c>>2, t=c&3, isK=!(t&1), f=(pi&15)*2+(t>>1).
__device__ void fold_paper_dev(const float* __restrict__ kqvW, const float* __restrict__ kqvb,
                               const float* __restrict__ Wk, const float* __restrict__ Wv,
                               const float* __restrict__ p,
                               float* __restrict__ Wt, float* __restrict__ bt, int bid) {
    int c = bid * 4 + (threadIdx.x >> 6);  // 0..191
    int i = threadIdx.x & 63;
    const float rsq = 0.1767766952966369f;
    if (c < 128) {
        int pi = c >> 2, t = c & 3;
        int h = pi >> 4, f = ((pi & 15) << 1) + (t >> 1);
        bool isK = (t & 1) == 0;
        const float* M = isK ? Wk : Wv;
        float sc = isK ? p[h] * rsq : 1.f;
        int srcbase = (isK ? 0 : 128) + h * 32;
        float acc = 0.f;
        for (int d = 0; d < 32; ++d)
            acc += kqvW[i * 192 + srcbase + d] * M[(h * 32 + d) * 32 + f];
        Wt[i * 192 + c] = acc * sc;
        if (i == 0) {
            float bb = 0.f;
            for (int d = 0; d < 32; ++d)
                bb += kqvb[srcbase + d] * M[(h * 32 + d) * 32 + f];
            bt[c] = bb * sc;
        }
    } else {
        Wt[i * 192 + c] = kqvW[i * 192 + 64 + (c - 128)];
        if (i == 0) bt[c] = kqvb[64 + (c - 128)];
    }
}

__device__ void fold_author_dev(const float* __restrict__ kqvW, const float* __restrict__ kqvb,
                                const float* __restrict__ Wk, const float* __restrict__ Wv,
                                const float* __restrict__ p,
                                float* __restrict__ Wt, float* __restrict__ bt, int bid) {
    int c = bid * 4 + (threadIdx.x >> 6);  // 0..127
    int i = threadIdx.x & 63;
    const float rsq = 0.1767766952966369f;
    int pi = c >> 2, t = c & 3;
    int h = pi >> 4, f = ((pi & 15) << 1) + (t >> 1);
    bool isK = (t & 1) == 0;
    const float* M = isK ? Wk : Wv;
    float sc = isK ? p[h] * rsq : 1.f;
    int srcbase = (isK ? 0 : 128) + h * 32;
    float acc = 0.f;
    for (int d = 0; d < 32; ++d)
        acc += kqvW[i * 192 + srcbase + d] * M[(h * 32 + d) * 32 + f];
    Wt[i * 128 + c] = acc * sc;
    if (i == 0) {
        float bb = 0.f;
        for (int d = 0; d < 32; ++d)
            bb += kqvb[srcbase + d] * M[(h * 32 + d) * 32 + f];
        bt[c] = bb * sc;
    }
}

// ---------------- CSR helpers ----------------
__device__ void deg_count_dev(const int* __restrict__ d1, const int* __restrict__ d2,
                              int* __restrict__ deg, int bid, int nblocks) {
    int stride = nblocks * 256;
    for (int i = bid * 256 + threadIdx.x; i < 2 * NE; i += stride) {
        int d = (i < NE) ? d1[i] : d2[i - NE];
        atomicAdd(deg + d, 1);
    }
}

__device__ __forceinline__ int block_excl_scan_256(int v) {
    __shared__ int wsum[4];
    int lane = threadIdx.x & 63, wv = threadIdx.x >> 6;
    int incl = v;
#pragma unroll
    for (int off = 1; off < 64; off <<= 1) {
        int t = __shfl_up(incl, off, 64);
        if (lane >= off) incl += t;
    }
    if (lane == 63) wsum[wv] = incl;
    __syncthreads();
    int wo = 0;
#pragma unroll
    for (int k = 0; k < 4; ++k) wo += (k < wv) ? wsum[k] : 0;
    __syncthreads();
    return wo + incl - v;
}

__device__ void scan_bsum_dev(const int* __restrict__ deg, int* __restrict__ bsum,
                              int n, int bid) {
    __shared__ int wsum[4];
    int i = bid * 256 + threadIdx.x;
    int v = (i < n) ? deg[i] : 0;
#pragma unroll
    for (int off = 32; off > 0; off >>= 1) v += __shfl_xor(v, off, 64);
    int lane = threadIdx.x & 63, wv = threadIdx.x >> 6;
    if (lane == 0) wsum[wv] = v;
    __syncthreads();
    if (threadIdx.x == 0) bsum[bid] = wsum[0] + wsum[1] + wsum[2] + wsum[3];
}

__global__ void scan_mid(int* __restrict__ bsum, int nb) {
    __shared__ int carry;
    if (threadIdx.x == 0) carry = 0;
    __syncthreads();
    for (int base = 0; base < nb; base += 256) {
        int i = base + threadIdx.x;
        int v = (i < nb) ? bsum[i] : 0;
        int ex = block_excl_scan_256(v);
        int c = carry;
        __syncthreads();
        if (i < nb) bsum[i] = ex + c;
        if (threadIdx.x == 255) carry = c + ex + v;
        __syncthreads();
    }
}

__global__ void scan_final(const int* __restrict__ deg, const int* __restrict__ bsum,
                           int* __restrict__ row_ptr, int* __restrict__ cursor, int n) {
    int i = blockIdx.x * 256 + threadIdx.x;
    int v = (i < n) ? deg[i] : 0;
    int ex = block_excl_scan_256(v) + bsum[blockIdx.x];
    if (i < n) { row_ptr[i] = ex; cursor[i] = ex; }
}

// fused scatter: blocks [0,SB) writes rel, [SB,2*SB) cites rel
__global__ void mega_scatter(const int* __restrict__ w_src, const int* __restrict__ w_dst,
                             const int* __restrict__ c_src, const int* __restrict__ c_dst,
                             int* __restrict__ cursor, int* __restrict__ payload, int SB) {
    int bid = blockIdx.x;
    const int* src = (bid < SB) ? w_src : c_src;
    const int* dst = (bid < SB) ? w_dst : c_dst;
    int relbit = (bid < SB) ? 0 : (1 << 30);
    int b = (bid < SB) ? bid : bid - SB;
    int e = b * 256 + threadIdx.x;
    if (e < NE) {
        int d = dst[e];
        int pos = atomicAdd(cursor + d, 1);
        payload[pos] = src[e] | relbit;
    }
}

// ---------------- mega kernels ----------------
#define FOLD_P_B 48
#define FOLD_A_B 32
#define LIN_XP_B 512
#define LIN_XA_B 256
#define DEG_B 512
#define MEGA1_B (FOLD_P_B + FOLD_A_B + LIN_XP_B + LIN_XA_B + DEG_B)

__global__ __launch_bounds__(256) void mega1(
    const float* x_paper, const float* x_author,
    const float* linWp, const float* linbp, const float* linWa, const float* linba,
    const float* kqvWp, const float* kqvbp, const float* kqvWa, const float* kqvba,
    const float* Wk_w, const float* Wv_w, const float* p_w,
    const float* Wk_c, const float* Wv_c, const float* p_c,
    const int* w_dst, const int* c_dst,
    float* xp, float* xa, float* WtP, float* btP, float* WtA, float* btA,
    int* deg) {
    __shared__ float blob[16640];
    int bid = blockIdx.x;
    if (bid < FOLD_P_B) {
        fold_paper_dev(kqvWp, kqvbp, Wk_c, Wv_c, p_c, WtP, btP, bid);
    } else if (bid < FOLD_P_B + FOLD_A_B) {
        fold_author_dev(kqvWa, kqvba, Wk_w, Wv_w, p_w, WtA, btA, bid - FOLD_P_B);
    } else if (bid < FOLD_P_B + FOLD_A_B + LIN_XP_B) {
        lin2_dev<INDIM, FF, true>(blob, x_paper, linWp, linbp, xp, NP,
                                  bid - (FOLD_P_B + FOLD_A_B), LIN_XP_B);
    } else if (bid < FOLD_P_B + FOLD_A_B + LIN_XP_B + LIN_XA_B) {
        lin2_dev<INDIM, FF, true>(blob, x_author, linWa, linba, xa, NA,
                                  bid - (FOLD_P_B + FOLD_A_B + LIN_XP_B), LIN_XA_B);
    } else {
        deg_count_dev(w_dst, c_dst, deg, bid - (FOLD_P_B + FOLD_A_B + LIN_XP_B + LIN_XA_B), DEG_B);
    }
}

#define LIN_PG_B 512
#define LIN_AG_B 256
#define NB_SCAN 782   // ceil(NP/256)
#define MEGA2_B (LIN_PG_B + LIN_AG_B + NB_SCAN)

__global__ __launch_bounds__(256) void mega2(
    const float* xp, const float* xa,
    const float* WtP, const float* btP, const float* WtA, const float* btA,
    float* pG, float* aG, const int* deg, int* bsum) {
    __shared__ float blob[16640];
    int bid = blockIdx.x;
    if (bid < LIN_PG_B) {
        lin2_dev<FF, 192, false>(blob, xp, WtP, btP, pG, NP, bid, LIN_PG_B);
    } else if (bid < LIN_PG_B + LIN_AG_B) {
        lin2_dev<FF, 128, false>(blob, xa, WtA, btA, aG, NA, bid - LIN_PG_B, LIN_AG_B);
    } else {
        scan_bsum_dev(deg, bsum, NP, bid - (LIN_PG_B + LIN_AG_B));
    }
}

// ---------------- wave-per-dst aggregation: 2 edges/wave, float4 gathers ----
// lanes 0-31 edge j, lanes 32-63 edge j+1. lane pair index pi=lane&31:
// h=pi>>4, f0=(pi&15)*2. float4 = (k_f0, v_f0, k_f1, v_f1). dot = 2 fma +
// 4-shuffle 16-lane reduce. Halves merged once per dst via shfl_xor 32.
__global__ void csr_agg(const float* __restrict__ pG, const float* __restrict__ aG,
                        const int* __restrict__ row_ptr, const int* __restrict__ deg,
                        const int* __restrict__ payload, float* __restrict__ agg) {
    const int lane = threadIdx.x & 63;
    const int pi = lane & 31;
    const int half = lane >> 5;
    const int h = pi >> 4;
    const int f0 = (pi & 15) << 1;
    int wave_id = (blockIdx.x * blockDim.x + threadIdx.x) >> 6;
    int nwaves = (gridDim.x * blockDim.x) >> 6;
    for (int n = wave_id; n < NP; n += nwaves) {
        const float* qb = pG + (size_t)n * 192 + 128 + h * 32 + f0;
        float2 q2 = *(const float2*)qb;
        int start = row_ptr[n], dg = deg[n];
        float s = 0.f;
        float ax = 0.f, ay = 0.f;
        for (int j = 0; j < dg; j += 4) {
            int jA = j + half;
            int jB = j + 2 + half;
            bool okA = jA < dg, okB = jB < dg;
            int plA = payload[start + (okA ? jA : 0)];
            int plB = payload[start + (okB ? jB : 0)];
            int relA = (int)((unsigned)plA >> 30), relB = (int)((unsigned)plB >> 30);
            int snA = plA & 0x3FFFFFFF, snB = plB & 0x3FFFFFFF;
            const float* baseA = relA ? (pG + (size_t)snA * 192) : (aG + (size_t)snA * 128);
            const float* baseB = relB ? (pG + (size_t)snB * 192) : (aG + (size_t)snB * 128);
            float4 fA = *(const float4*)(baseA + 4 * pi);
            float4 fB = *(const float4*)(baseB + 4 * pi);
            float dA = q2.x * fA.x + q2.y * fA.z;
            float dB = q2.x * fB.x + q2.y * fB.z;
#pragma unroll
            for (int off = 1; off < 16; off <<= 1) {
                dA += __shfl_xor(dA, off, 64);
                dB += __shfl_xor(dB, off, 64);
            }
            float eA = __expf(dA) * (okA ? 1.f : 0.f);
            float eB = __expf(dB) * (okB ? 1.f : 0.f);
            s += eA + eB;
            ax = fmaf(eA, fA.y, ax); ax = fmaf(eB, fB.y, ax);
            ay = fmaf(eA, fA.w, ay); ay = fmaf(eB, fB.w, ay);
        }
        s  += __shfl_xor(s, 32, 64);
        ax += __shfl_xor(ax, 32, 64);
        ay += __shfl_xor(ay, 32, 64);
        if (half == 0) {
            float inv = 1.f / fmaxf(s, 1e-16f);
            float2 o; o.x = ax * inv; o.y = ay * inv;
            *(float2*)(agg + (size_t)n * 64 + h * 32 + f0) = o;
        }
    }
}

// ---------------- fused epilogue (register-blocked, known-good) ----------
__global__ __launch_bounds__(256) void finalize2(const float* __restrict__ agg,
                                                 const float* __restrict__ xp,
                                                 const float* __restrict__ aW,
                                                 const float* __restrict__ ab,
                                                 const float* __restrict__ skip,
                                                 const float* __restrict__ outW,
                                                 const float* __restrict__ outb,
                                                 float* __restrict__ out) {
    __shared__ float As[64 * 64];
    __shared__ float Gs[64 * 68];
    for (int i = threadIdx.x; i < 64 * 64 / 4; i += 256)
        ((float4*)As)[i] = ((const float4*)aW)[i];
    const int ty = threadIdx.x >> 4;
    const int tx = threadIdx.x & 15;
    const int c0 = tx * 4;
    const float sp = 1.f / (1.f + expf(-skip[0]));
    const float ob = outb[0];
    float4 ab4 = *(const float4*)(ab + c0);
    float4 oW4 = *(const float4*)(outW + c0);
    const int ntiles = NP >> 6;
    for (int tile = blockIdx.x; tile < ntiles; tile += gridDim.x) {
        const int base = tile << 6;
        __syncthreads();
        for (int i = threadIdx.x; i < 64 * 16; i += 256) {
            int r = i >> 4;
            int k4 = (i & 15) * 4;
            float4 v = *(const float4*)(agg + (size_t)(base + r) * 64 + k4);
            v.x = 0.5f * v.x * (1.f + erff(v.x * 0.7071067811865476f));
            v.y = 0.5f * v.y * (1.f + erff(v.y * 0.7071067811865476f));
            v.z = 0.5f * v.z * (1.f + erff(v.z * 0.7071067811865476f));
            v.w = 0.5f * v.w * (1.f + erff(v.w * 0.7071067811865476f));
            *(float4*)(Gs + r * 68 + k4) = v;
        }
        __syncthreads();
        float acc[4][4];
#pragma unroll
        for (int j = 0; j < 4; ++j) {
            acc[j][0] = ab4.x; acc[j][1] = ab4.y; acc[j][2] = ab4.z; acc[j][3] = ab4.w;
        }
        for (int k4 = 0; k4 < 64; k4 += 4) {
            float4 xr[4];
#pragma unroll
            for (int j = 0; j < 4; ++j)
                xr[j] = *(const float4*)(Gs + (ty * 4 + j) * 68 + k4);
            float4 wv[4];
#pragma unroll
            for (int kk = 0; kk < 4; ++kk)
                wv[kk] = *(const float4*)(As + (k4 + kk) * 64 + c0);
#pragma unroll
            for (int kk = 0; kk < 4; ++kk) {
#pragma unroll
                for (int j = 0; j < 4; ++j) {
                    float xk[4] = {xr[j].x, xr[j].y, xr[j].z, xr[j].w};
                    float xv = xk[kk];
                    acc[j][0] = fmaf(xv, wv[kk].x, acc[j][0]);
                    acc[j][1] = fmaf(xv, wv[kk].y, acc[j][1]);
                    acc[j][2] = fmaf(xv, wv[kk].z, acc[j][2]);
                    acc[j][3] = fmaf(xv, wv[kk].w, acc[j][3]);
                }
            }
        }
#pragma unroll
        for (int j = 0; j < 4; ++j) {
            int row = base + ty * 4 + j;
            float4 xv = *(const float4*)(xp + (size_t)row * 64 + c0);
            float t = (sp * acc[j][0] + (1.f - sp) * xv.x) * oW4.x;
            t = fmaf(sp * acc[j][1] + (1.f - sp) * xv.y, oW4.y, t);
            t = fmaf(sp * acc[j][2] + (1.f - sp) * xv.z, oW4.z, t);
            t = fmaf(sp * acc[j][3] + (1.f - sp) * xv.w, oW4.w, t);
#pragma unroll
            for (int off = 1; off < 16; off <<= 1) t += __shfl_xor(t, off, 64);
            if (tx == 0) out[row] = t + ob;
        }
    }
}

extern "C" void kernel_launch(void* const* d_in, const int* in_sizes, int n_in,
                              void* d_out, int out_size, void* d_ws, size_t ws_size,
                              hipStream_t stream) {
    const float* x_paper  = (const float*)d_in[0];
    const float* x_author = (const float*)d_in[1];
    const int*   w_src    = (const int*)d_in[2];
    const int*   w_dst    = (const int*)d_in[3];
    const int*   c_src    = (const int*)d_in[4];
    const int*   c_dst    = (const int*)d_in[5];
    const float* linWp = (const float*)d_in[8];
    const float* linbp = (const float*)d_in[9];
    const float* linWa = (const float*)d_in[10];
    const float* linba = (const float*)d_in[11];
    const float* kqvWp = (const float*)d_in[12];
    const float* kqvbp = (const float*)d_in[13];
    const float* kqvWa = (const float*)d_in[14];
    const float* kqvba = (const float*)d_in[15];
    const float* aWp   = (const float*)d_in[16];
    const float* abp   = (const float*)d_in[17];
    const float* skipp = (const float*)d_in[20];
    const float* Wk_w  = (const float*)d_in[22];
    const float* Wv_w  = (const float*)d_in[23];
    const float* p_w   = (const float*)d_in[24];
    const float* Wk_c  = (const float*)d_in[25];
    const float* Wv_c  = (const float*)d_in[26];
    const float* p_c   = (const float*)d_in[27];
    const float* outW  = (const float*)d_in[31];
    const float* outb  = (const float*)d_in[32];
    float* out = (float*)d_out;

    // workspace layout (floats) — ~339 MB
    float* ws   = (float*)d_ws;
    float* xp   = ws;                            // NP*64
    float* xa   = xp + (size_t)NP * FF;          // NA*64
    float* pG   = xa + (size_t)NA * FF;          // NP*192  [frag128 | q64]
    float* aG   = pG + (size_t)NP * 192;         // NA*128  [frag128]
    float* agg  = aG + (size_t)NA * 128;         // NP*64
    float* WtP  = agg + (size_t)NP * FF;         // 64*192
    float* btP  = WtP + 64 * 192;                // 192
    float* WtA  = btP + 192;                     // 64*128
    float* btA  = WtA + 64 * 128;                // 128
    int* deg     = (int*)(btA + 128);            // NP
    int* row_ptr = deg + NP;                     // NP
    int* cursor  = row_ptr + NP;                 // NP
    int* bsum    = cursor + NP;                  // 1024
    int* payload = bsum + 1024;                  // 2*NE

    hipMemsetAsync(deg, 0, (size_t)NP * sizeof(int), stream);

    dim3 blk(256);
    const int SB = (NE + 255) / 256;  // 1563

    mega1<<<MEGA1_B, blk, 0, stream>>>(x_paper, x_author, linWp, linbp, linWa, linba,
                                       kqvWp, kqvbp, kqvWa, kqvba,
                                       Wk_w, Wv_w, p_w, Wk_c, Wv_c, p_c,
                                       w_dst, c_dst,
                                       xp, xa, WtP, btP, WtA, btA, deg);

    mega2<<<MEGA2_B, blk, 0, stream>>>(xp, xa, WtP, btP, WtA, btA, pG, aG, deg, bsum);

    scan_mid<<<1, blk, 0, stream>>>(bsum, NB_SCAN);
    scan_final<<<NB_SCAN, blk, 0, stream>>>(deg, bsum, row_ptr, cursor, NP);

    mega_scatter<<<2 * SB, blk, 0, stream>>>(w_src, w_dst, c_src, c_dst, cursor, payload, SB);

    csr_agg<<<4096, blk, 0, stream>>>(pG, aG, row_ptr, deg, payload, agg);

    finalize2<<<1024, blk, 0, stream>>>(agg, xp, aWp, abp, skipp, outW, outb, out);
}